// Round 13
// baseline (247.458 us; speedup 1.0000x reference)
//
#include <hip/hip_runtime.h>
#include <math.h>

#define TPB 192

typedef __attribute__((ext_vector_type(8))) short bf16x8;
typedef __attribute__((ext_vector_type(4))) float f32x4;

// ---- LDS layout (float offsets), lifetime-overlaid. ----
// x    [0,784)      f32 input; dead after dyn
// xbf0 [784,1264)   x bf16 [30 row][32 col] (pads zero); dead after conv7
// xbf1 [1264,1744)  flat-shifted copy (xbf1[e]=xbf0[e+1]) for odd-col dword
//                   alignment; dead after conv7
// Xi   [1744,4816)  conv7 im2col B [96 n][64 k] bf16, XOR-swz (k8^=(n&7)<<3);
//                   n = pp*48+rr*24+col (pair-local). Dead after conv7.
// C7   [4816,6736)  conv7 MFMA out [96 n][20 oc-pad] f32; dead after conv7
// c1b  [6736,7264)  conv7 pooled out bf16 [11][12][8]; dead after conv5
// C5   [1744,2704)  conv5 MFMA out [48][20] f32 (over dead Xi)
// y2   [784,2656)   dyn out bf16 [13][12][24] (over dead xbf/Xi)
// f    [2704,2794)  conv5 pooled (outside y2-zero range!)
// h    [2796,2828)  fc1 out;  k [2828,2868) dyn kernels
// C2   [2868,5172)  conv2 MFMA out [64][36] f32 (over dead Xi/C7)
// p3 [0,320) pf [320,420) a1 [420,470) z [472,482)  (over dead x)
#define OX    0
#define OXB0  784
#define OXB1  1264
#define OXI   1744
#define OC7   4816
#define OC1B  6736
#define OC5   1744
#define OY2   784
#define OF    2704
#define OH    2796
#define OK2   2828
#define OC2S  2868
#define OP3   0
#define OPF   320
#define OA1   420
#define OZ    472
#define SM_TOT 7264   // 29056 B -> 5 blocks/CU (occupancy knobs null all session)

// Packed weights in d_ws (ushort units):
// W3 [5 kx][3 kyp][20 oc][32 k] @ 0      — conv2 A
// W5 [7 s][16 oc][32 k]        @ 9600   — conv5 A
// W7 [2 s][16 oc][32 k]        @ 13184  — conv7 A; k=kyl*8+kx, ky=4s+kyl
#define W3U 0
#define W5U 9600
#define W7U 13184
#define WSU_TOT 14208   // 28416 B <= 33408 (R5-verified ws floor)

__device__ __forceinline__ unsigned short f2bf(float f) {
    unsigned int u = __float_as_uint(f);
    u += 0x7FFF + ((u >> 16) & 1);          // round-to-nearest-even
    return (unsigned short)(u >> 16);
}

__global__ void repack_w(const float* __restrict__ conv2_w,
                         const float* __restrict__ kf_w2,
                         const float* __restrict__ kf_w1,
                         unsigned short* __restrict__ ws)
{
    int i = blockIdx.x * blockDim.x + threadIdx.x;
    if (i < 9600) {            // W3
        int g = i / 640, rem = i % 640;
        int oc = rem >> 5, k = rem & 31;
        int kyp = g % 3, kx = g / 3;
        int kyip = k >> 4, ic = k & 15, ky = 2 * kyp + kyip;
        float v = 0.f;
        if (ic < 10 && ky < 5)
            v = conv2_w[(oc * 10 + ic) * 25 + ky * 5 + kx];
        ws[W3U + i] = f2bf(v);
    } else if (i < 13184) {    // W5
        int j = i - 9600;
        int s = j >> 9, rem = j & 511;
        int oc = rem >> 5, k = rem & 31;
        int tap = 4 * s + (k >> 3), ic = k & 7;
        float v = 0.f;
        if (oc < 10 && tap < 25)
            v = kf_w2[(oc * 8 + ic) * 25 + tap];
        ws[W5U + j] = f2bf(v);
    } else if (i < WSU_TOT) {  // W7
        int j = i - 13184;     // 0..1023
        int s = j >> 9, oc = (j >> 5) & 15, k = j & 31;
        int ky = s * 4 + (k >> 3), kx = k & 7;
        float v = 0.f;
        if (oc < 8 && kx < 7 && ky < 7)
            v = kf_w1[oc * 49 + ky * 7 + kx];
        ws[W7U + j] = f2bf(v);
    }
}

// R13: conv7 -> MFMA (the last big FMA block; issue-bound law: R4/R11/R12
// wins all cut the stream). ic=1 forces im2col: k=ky*8+kx so a fragment
// k-slice = 8 contiguous x pixels; dual bf16 x-copies (xbf0/xbf1 shifted)
// give 4B-aligned staging reads at any col parity; Xi XOR-swizzled (T2)
// to kill the stride-128B bank pathology. 6 iters x {MFMA | bar |
// stage-next+pool | bar}; single Xi/C7 buffers suffice with this order.
// K/M pads via zero weights (staged B always finite -> no NaN*0).
__global__ __launch_bounds__(TPB) void fused_forward(
    const float* __restrict__ x,
    const float* __restrict__ kf_w1, const float* __restrict__ kf_b1,
    const float* __restrict__ kf_w2, const float* __restrict__ kf_b2,
    const float* __restrict__ kf_fc1_w, const float* __restrict__ kf_fc1_b,
    const float* __restrict__ kf_fc2_w, const float* __restrict__ kf_fc2_b,
    const float* __restrict__ conv2_w, const float* __restrict__ conv2_b,
    const float* __restrict__ fc1_w, const float* __restrict__ fc1_b,
    const float* __restrict__ fc2_w, const float* __restrict__ fc2_b,
    const unsigned short* __restrict__ wsu,
    float* __restrict__ out)
{
    __shared__ __align__(16) float sm[SM_TOT];
    const int tid = threadIdx.x;
    const int n = blockIdx.x;

    const float bias1 = kf_b1[tid & 7];   // hoisted for conv7 pool

    // ---- stage 0: x f32 (float4) + zero xbf0/xbf1 ----
    {
        const float4* xg = (const float4*)(x + (long long)n * 784);
        float4* d = (float4*)&sm[OX];
        for (int i = tid; i < 196; i += TPB) d[i] = xg[i];
        float4* z4 = (float4*)&sm[OXB0];            // 960 f = 240 float4
        for (int i = tid; i < 240; i += TPB) z4[i] = float4{0.f, 0.f, 0.f, 0.f};
    }
    __syncthreads();

    // ---- fill xbf0 [30][32] + xbf1 (flat shift-by-1) from x ----
    if (tid < 196) {
        float4 v = *(const float4*)&sm[OX + tid * 4];
        unsigned short* b0 = (unsigned short*)&sm[OXB0];
        unsigned short* b1 = (unsigned short*)&sm[OXB1];
        #pragma unroll
        for (int j = 0; j < 4; ++j) {
            int e = tid * 4 + j;                    // 0..783 linear
            int row = e / 28, c = e - row * 28;
            unsigned short bv = f2bf(((const float*)&v)[j]);
            int pos = row * 32 + c;
            b0[pos] = bv;
            if (pos > 0) b1[pos - 1] = bv;
        }
    }
    __syncthreads();

    // ---- conv7 via MFMA over pooled-row pairs ----
    // stage Xi for pair `it`: 768 tasks (n 0..95 x ky 0..7), 4/thread.
    // Xi[n][k], k=ky*8+kx: src = x[4it+2pp+rr+ky][col+kx], kx=0..7
    // = 4 aligned dwords from xbf0 (col even) / xbf1 (col odd).
    auto stageXi = [&](int it) {
        unsigned short* Xi = (unsigned short*)&sm[OXI];
        const int* b0 = (const int*)&sm[OXB0];
        const int* b1 = (const int*)&sm[OXB1];
        #pragma unroll
        for (int i = 0; i < 4; ++i) {
            int t = tid + 192 * i;
            int nn = t % 96, ky = t / 96;           // lanes sweep n: bank-spread
            int pp = nn >= 48 ? 1 : 0;
            int rem = nn - pp * 48;
            int rr = rem >= 24 ? 1 : 0;
            int col = rem - rr * 24;
            int row = 4 * it + 2 * pp + rr + ky;
            row = row > 29 ? 29 : row;              // clamp (zero/garbage rows ok)
            const int* src = (col & 1) ? (b1 + row * 16 + (col >> 1))
                                       : (b0 + row * 16 + (col >> 1));
            int4 w4;
            w4.x = src[0]; w4.y = src[1]; w4.z = src[2]; w4.w = src[3];
            *(int4*)(Xi + nn * 64 + ((ky * 8) ^ ((nn & 7) << 3))) = w4;
        }
    };

    stageXi(0);
    __syncthreads();

    for (int it = 0; it < 6; ++it) {
        // MFMA: 3 waves x 2 n-tiles (base wv*16, 48+wv*16) x 2 k-steps
        {
            const int wv = tid >> 6, l = tid & 63;
            const int lm = l & 15, lk = l >> 4;
            const unsigned short* Xi = (const unsigned short*)&sm[OXI];
            const unsigned short* W7 = wsu + W7U;
            const int n0 = wv * 16 + lm, n1 = n0 + 48;
            f32x4 acc0 = {0.f, 0.f, 0.f, 0.f};
            f32x4 acc1 = {0.f, 0.f, 0.f, 0.f};
            #pragma unroll
            for (int s = 0; s < 2; ++s) {
                bf16x8 A = *(const bf16x8*)(W7 + s * 512 + lm * 32 + lk * 8);
                bf16x8 B0 = *(const bf16x8*)(Xi + n0 * 64 + ((s * 32 + lk * 8) ^ ((n0 & 7) << 3)));
                bf16x8 B1 = *(const bf16x8*)(Xi + n1 * 64 + ((s * 32 + lk * 8) ^ ((n1 & 7) << 3)));
                acc0 = __builtin_amdgcn_mfma_f32_16x16x32_bf16(A, B0, acc0, 0, 0, 0);
                acc1 = __builtin_amdgcn_mfma_f32_16x16x32_bf16(A, B1, acc1, 0, 0, 0);
            }
            float* C7 = &sm[OC7];
            *(f32x4*)(C7 + n0 * 20 + lk * 4) = acc0;   // C: col=lm(n), row(oc)=lk*4+reg
            *(f32x4*)(C7 + n1 * 20 + lk * 4) = acc1;
        }
        __syncthreads();

        // stage next pair + pool this pair's C7 -> c1b
        if (it < 5) stageXi(it + 1);
        if (tid < 176) {
            int oc = tid & 7, r = tid >> 3;        // r 0..21
            int c = r % 11, pp = r / 11;
            int p = 2 * it + pp;
            if (p < 11) {
                const float* C7 = &sm[OC7];
                int nb = pp * 48 + 2 * c;
                float v00 = C7[nb * 20 + oc];
                float v01 = C7[(nb + 1) * 20 + oc];
                float v10 = C7[(nb + 24) * 20 + oc];
                float v11 = C7[(nb + 25) * 20 + oc];
                float m = fmaxf(fmaxf(v00, v01), fmaxf(v10, v11)) + bias1;
                ((unsigned short*)&sm[OC1B])[p * 96 + c * 8 + oc] = f2bf(fmaxf(m, 0.f));
            }
        }
        __syncthreads();
    }

    // ---- conv5 via MFMA: 3 waves x 1 N-tile x 7 k-steps -> C5[48][20] ----
    {
        const int wv = tid >> 6, l = tid & 63;
        const int lm = l & 15, lq = l >> 4;
        int nn = wv * 16 + lm;
        int nc = nn > 35 ? 35 : nn;            // clamp pad lanes (garbage ok)
        const int rr = nc / 6, cc = nc - rr * 6;
        const unsigned short* c1b = (const unsigned short*)&sm[OC1B];
        const char* W5 = (const char*)(wsu + W5U);
        f32x4 acc = {0.f, 0.f, 0.f, 0.f};
        #pragma unroll
        for (int s = 0; s < 7; ++s) {
            int tap = 4 * s + lq;
            int ky = (tap * 13) >> 6;          // tap/5 for tap<=27
            int kx = tap - ky * 5;
            bf16x8 A = *(const bf16x8*)(W5 + s * 1024 + lm * 64 + lq * 16);
            bf16x8 B = *(const bf16x8*)(c1b + (rr + ky) * 96 + (cc + kx) * 8);
            acc = __builtin_amdgcn_mfma_f32_16x16x32_bf16(A, B, acc, 0, 0, 0);
        }
        *(f32x4*)(&sm[OC5] + nn * 20 + lq * 4) = acc;
    }
    __syncthreads();

    // ---- conv5 pool: C5 pre-pool 6x6 -> f[10][9] + bias + relu ----
    if (tid < 90) {
        int oc = tid % 10, rr = tid / 10;      // rr = py*3+px
        int py = rr / 3, px = rr % 3;
        const float* C5 = &sm[OC5];
        int nb = (2 * py) * 6 + 2 * px;
        float v = fmaxf(fmaxf(C5[nb * 20 + oc], C5[(nb + 1) * 20 + oc]),
                        fmaxf(C5[(nb + 6) * 20 + oc], C5[(nb + 7) * 20 + oc]));
        sm[OF + oc * 9 + rr] = fmaxf(v + kf_b2[oc], 0.f);
    }
    __syncthreads();

    // ---- wave 0: fc 90->32 + relu, fc 32->40 (no barrier between);
    //      waves 1-2: zero y2 [784,2656) (f/h at 2704+ untouched) ----
    if (tid < 32) {
        float acc = kf_fc1_b[tid];
        const float2* wr = (const float2*)&kf_fc1_w[tid * 90];
        const float2* ff = (const float2*)&sm[OF];
        for (int i = 0; i < 45; ++i) {
            float2 wv = wr[i], fv = ff[i];
            acc = fmaf(wv.x, fv.x, acc);
            acc = fmaf(wv.y, fv.y, acc);
        }
        sm[OH + tid] = fmaxf(acc, 0.f);
    }
    if (tid < 40) {
        float acc = kf_fc2_b[tid];
        const float4* wr = (const float4*)&kf_fc2_w[tid * 32];
        const float4* hh = (const float4*)&sm[OH];
        #pragma unroll
        for (int i = 0; i < 8; ++i) {
            float4 wv = wr[i], hv = hh[i];
            acc = fmaf(wv.x, hv.x, acc);
            acc = fmaf(wv.y, hv.y, acc);
            acc = fmaf(wv.z, hv.z, acc);
            acc = fmaf(wv.w, hv.w, acc);
        }
        sm[OK2 + tid] = acc;
    }
    if (tid >= 64) {
        float4* z4 = (float4*)&sm[OY2];          // 1872 f = 468 float4
        for (int i = tid - 64; i < 468; i += 128) z4[i] = float4{0.f, 0.f, 0.f, 0.f};
    }
    __syncthreads();

    // ---- dynamic 2x2 conv + pool + relu -> y2 bf16 [row][col][ic] ----
    if (tid < 120) {
        int oc = tid % 10, py = tid / 10;      // py 0..11
        float4 kv = *(const float4*)&sm[OK2 + oc * 4];
        float k0 = kv.x, k1 = kv.y, k2 = kv.z, k3 = kv.w;
        const float* x0 = &sm[OX + 2 * py * 28];
        const float* x1 = x0 + 28;
        const float* x2 = x0 + 56;
        float2 q0 = *(const float2*)&x0[0];
        float2 q1 = *(const float2*)&x1[0];
        float2 q2 = *(const float2*)&x2[0];
        float A0 = q0.x, B0 = q0.y;
        float A1 = q1.x, B1 = q1.y;
        float A2 = q2.x, B2 = q2.y;
        unsigned short* y2 = (unsigned short*)&sm[OY2];
        #pragma unroll
        for (int j = 0; j < 12; ++j) {
            float2 r0 = *(const float2*)&x0[2 * j + 2];
            float2 r1 = *(const float2*)&x1[2 * j + 2];
            float2 r2v = *(const float2*)&x2[2 * j + 2];
            float C0 = r0.x, C1 = r1.x, C2 = r2v.x;
            float c00 = A0 * k0 + B0 * k1 + A1 * k2 + B1 * k3;
            float c01 = B0 * k0 + C0 * k1 + B1 * k2 + C1 * k3;
            float c10 = A1 * k0 + B1 * k1 + A2 * k2 + B2 * k3;
            float c11 = B1 * k0 + C1 * k1 + B2 * k2 + C2 * k3;
            float m = fmaxf(fmaxf(c00, c01), fmaxf(c10, c11));
            y2[py * 288 + j * 24 + oc] = f2bf(fmaxf(m, 0.f));
            A0 = C0; A1 = C1; A2 = C2;
            B0 = r0.y; B1 = r1.y; B2 = r2v.y;
        }
    }
    __syncthreads();

    // ---- conv2 via MFMA: 2 waves x {2 M x 2 N tiles}; 15 k-steps ----
    {
        const int wv = tid >> 6;
        if (wv < 2) {
            const int l  = tid & 63;
            const int lm = l & 15, lk = l >> 4;
            f32x4 a00 = {0.f, 0.f, 0.f, 0.f};
            f32x4 a01 = a00, a10 = a00, a11 = a00;
            const char* W3 = (const char*)(wsu + W3U);
            const int aoff0 = lm * 64 + lk * 16;
            const int oc1 = 16 + (lm < 4 ? lm : 3);    // clamp: rows 20+ unused
            const int aoff1 = oc1 * 64 + lk * 16;
            const int n0 = wv * 32 + lm;
            const int n1 = n0 + 16;
            const int kyip = l >> 5, icb = (lk & 1) * 8;
            const unsigned short* Y2 = (const unsigned short*)&sm[OY2];
            const int b0 = ((n0 >> 3) + kyip) * 288 + (n0 & 7) * 24 + icb;
            const int b1 = ((n1 >> 3) + kyip) * 288 + (n1 & 7) * 24 + icb;
            #pragma unroll
            for (int p = 0; p < 3; ++p) {
                #pragma unroll
                for (int kx = 0; kx < 5; ++kx) {
                    const char* wa = W3 + (kx * 3 + p) * 1280;
                    bf16x8 A0 = *(const bf16x8*)(wa + aoff0);
                    bf16x8 A1 = *(const bf16x8*)(wa + aoff1);
                    const int bo = p * 576 + kx * 24;      // bf16 units
                    bf16x8 B0 = *(const bf16x8*)(Y2 + b0 + bo);
                    bf16x8 B1 = *(const bf16x8*)(Y2 + b1 + bo);
                    a00 = __builtin_amdgcn_mfma_f32_16x16x32_bf16(A0, B0, a00, 0, 0, 0);
                    a01 = __builtin_amdgcn_mfma_f32_16x16x32_bf16(A0, B1, a01, 0, 0, 0);
                    a10 = __builtin_amdgcn_mfma_f32_16x16x32_bf16(A1, B0, a10, 0, 0, 0);
                    a11 = __builtin_amdgcn_mfma_f32_16x16x32_bf16(A1, B1, a11, 0, 0, 0);
                }
            }
            float* C = &sm[OC2S];
            *(f32x4*)(C + n0 * 36 + lk * 4)      = a00;    // oc 0..15
            *(f32x4*)(C + n1 * 36 + lk * 4)      = a01;
            *(f32x4*)(C + n0 * 36 + 16 + lk * 4) = a10;    // oc 16..19 (+junk)
            *(f32x4*)(C + n1 * 36 + 16 + lk * 4) = a11;
        }
    }
    __syncthreads();

    // ---- pool C[64][36] + bias + relu -> p3[20,4,4] (80 threads) ----
    if (tid < 80) {
        int oc = tid % 20, py = tid / 20;      // py 0..3
        float b = conv2_b[oc];
        const float* C = &sm[OC2S];
        #pragma unroll
        for (int px = 0; px < 4; ++px) {
            int n00 = (2 * py) * 8 + 2 * px;
            float c00 = C[n00 * 36 + oc];
            float c01 = C[(n00 + 1) * 36 + oc];
            float c10 = C[(n00 + 8) * 36 + oc];
            float c11 = C[(n00 + 9) * 36 + oc];
            float m = fmaxf(fmaxf(c00, c01), fmaxf(c10, c11)) + b;
            sm[OP3 + oc * 16 + py * 4 + px] = fmaxf(m, 0.f);
        }
    }
    __syncthreads();

    // ---- fc 320->50, 2-way k-split (100 threads, 40 float4 each) ----
    if (tid < 100) {
        int g = tid / 50, o = tid % 50;
        const float4* wr4 = (const float4*)&fc1_w[o * 320 + g * 160];
        const float4* pp4 = (const float4*)&sm[OP3 + g * 160];
        float acc = 0.f;
        for (int i = 0; i < 40; ++i) {
            float4 wv = wr4[i], pv = pp4[i];
            acc = fmaf(wv.x, pv.x, acc);
            acc = fmaf(wv.y, pv.y, acc);
            acc = fmaf(wv.z, pv.z, acc);
            acc = fmaf(wv.w, pv.w, acc);
        }
        sm[OPF + tid] = acc;
    }
    __syncthreads();

    // ---- tail: wave 0, barrier-free (intra-wave LDS ordering) ----
    if (tid < 50) {
        float acc = fc1_b[tid] + sm[OPF + tid] + sm[OPF + 50 + tid];
        sm[OA1 + tid] = fmaxf(acc, 0.f);
    }
    if (tid < 10) {
        float acc = fc2_b[tid];
        const float2* wr = (const float2*)&fc2_w[tid * 50];
        #pragma unroll
        for (int i = 0; i < 25; ++i) {
            float2 wv = wr[i];
            acc = fmaf(wv.x, sm[OA1 + 2 * i], acc);
            acc = fmaf(wv.y, sm[OA1 + 2 * i + 1], acc);
        }
        sm[OZ + tid] = acc;
    }
    if (tid < 10) {
        float m = sm[OZ + 0];
        #pragma unroll
        for (int i = 1; i < 10; ++i) m = fmaxf(m, sm[OZ + i]);
        float s = 0.f;
        #pragma unroll
        for (int i = 0; i < 10; ++i) s += expf(sm[OZ + i] - m);
        out[n * 10 + tid] = sm[OZ + tid] - m - logf(s);
    }
}

extern "C" void kernel_launch(void* const* d_in, const int* in_sizes, int n_in,
                              void* d_out, int out_size, void* d_ws, size_t ws_size,
                              hipStream_t stream) {
    const float* x        = (const float*)d_in[0];
    const float* kf_w1    = (const float*)d_in[1];
    const float* kf_b1    = (const float*)d_in[2];
    const float* kf_w2    = (const float*)d_in[3];
    const float* kf_b2    = (const float*)d_in[4];
    const float* kf_fc1_w = (const float*)d_in[5];
    const float* kf_fc1_b = (const float*)d_in[6];
    const float* kf_fc2_w = (const float*)d_in[7];
    const float* kf_fc2_b = (const float*)d_in[8];
    const float* conv2_w  = (const float*)d_in[9];
    const float* conv2_b  = (const float*)d_in[10];
    const float* fc1_w    = (const float*)d_in[11];
    const float* fc1_b    = (const float*)d_in[12];
    const float* fc2_w    = (const float*)d_in[13];
    const float* fc2_b    = (const float*)d_in[14];

    const int N = in_sizes[0] / 784;   // 8192

    unsigned short* wsu = (unsigned short*)d_ws;   // 28416 B <= ws floor
    repack_w<<<(WSU_TOT + 255) / 256, 256, 0, stream>>>(conv2_w, kf_w2, kf_w1, wsu);

    fused_forward<<<N, TPB, 0, stream>>>(
        x, kf_w1, kf_b1, kf_w2, kf_b2, kf_fc1_w, kf_fc1_b, kf_fc2_w, kf_fc2_b,
        conv2_w, conv2_b, fc1_w, fc1_b, fc2_w, fc2_b, wsu, (float*)d_out);
}

// Round 14
// 216.177 us; speedup vs baseline: 1.1447x; 1.1447x over previous
//
#include <hip/hip_runtime.h>
#include <math.h>

#define TPB 192

typedef __attribute__((ext_vector_type(8))) short bf16x8;
typedef __attribute__((ext_vector_type(4))) float f32x4;

// ---- LDS layout (float offsets), lifetime-overlaid. ----
// x    [0,784)      f32 input; dead after dyn
// xbf4 [784,2720)   4 shifted bf16 copies of x, [4][30 row][32 col] stride
//                   968 ushorts/copy (968%32cols pad keeps 8B align; stride
//                   1936B = 484 dwords -> +4 banks per copy). copy s entry
//                   (r,m) = x[r][m+s] (pads 0). Dead after conv7.
// C7   [2720,5024)  conv7 MFMA out [192 n][12 oc-pad] f32 (stride 12 ->
//                   16B-aligned f32x4, real oc 0..7); dead after conv7
// c1b  [5024,5552)  conv7 pooled bf16 [11][12][8]; dead after conv5
// C5   [784,1744)   conv5 MFMA out [48][20] f32 (over dead xbf4)
// y2   [784,2656)   dyn bf16 [13][12][24] (over dead xbf4/C5)
// C2   [2720,5024)  conv2 MFMA out [64][36] f32 (over dead C7)
// f    [5552,5642)  conv5 pooled; h [5644,5676); k [5676,5716)
// p3 [0,320) pf [320,420) a1 [420,470) z [472,482)  (over dead x)
#define OX    0
#define OXB   784
#define OC7   2720
#define OC1B  5024
#define OC5   784
#define OY2   784
#define OC2S  2720
#define OF    5552
#define OH    5644
#define OK2   5676
#define OP3   0
#define OPF   320
#define OA1   420
#define OZ    472
#define SM_TOT 5716   // 22864 B -> 7 blocks/CU (R13 was 5; R13's idle = sync+occ)

// Packed weights in d_ws (ushort units) — identical to R13.
#define W3U 0
#define W5U 9600
#define W7U 13184
#define WSU_TOT 14208   // 28416 B <= 33408 (R5-verified ws floor)

__device__ __forceinline__ unsigned short f2bf(float f) {
    unsigned int u = __float_as_uint(f);
    u += 0x7FFF + ((u >> 16) & 1);          // round-to-nearest-even
    return (unsigned short)(u >> 16);
}

__global__ void repack_w(const float* __restrict__ conv2_w,
                         const float* __restrict__ kf_w2,
                         const float* __restrict__ kf_w1,
                         unsigned short* __restrict__ ws)
{
    int i = blockIdx.x * blockDim.x + threadIdx.x;
    if (i < 9600) {            // W3
        int g = i / 640, rem = i % 640;
        int oc = rem >> 5, k = rem & 31;
        int kyp = g % 3, kx = g / 3;
        int kyip = k >> 4, ic = k & 15, ky = 2 * kyp + kyip;
        float v = 0.f;
        if (ic < 10 && ky < 5)
            v = conv2_w[(oc * 10 + ic) * 25 + ky * 5 + kx];
        ws[W3U + i] = f2bf(v);
    } else if (i < 13184) {    // W5
        int j = i - 9600;
        int s = j >> 9, rem = j & 511;
        int oc = rem >> 5, k = rem & 31;
        int tap = 4 * s + (k >> 3), ic = k & 7;
        float v = 0.f;
        if (oc < 10 && tap < 25)
            v = kf_w2[(oc * 8 + ic) * 25 + tap];
        ws[W5U + j] = f2bf(v);
    } else if (i < WSU_TOT) {  // W7
        int j = i - 13184;     // 0..1023
        int s = j >> 9, oc = (j >> 5) & 15, k = j & 31;
        int ky = s * 4 + (k >> 3), kx = k & 7;
        float v = 0.f;
        if (oc < 8 && kx < 7 && ky < 7)
            v = kf_w1[oc * 49 + ky * 7 + kx];
        ws[W7U + j] = f2bf(v);
    }
}

// R14: conv7-MFMA without im2col. R13 cut VALUBusy 48.5->22 (-38us busy)
// but lost more to idle: 12 tiny-quantum barriers + 5 blocks/CU + staging
// conflicts. Fix: B-fragments read DIRECTLY from 4 shifted bf16 x-copies
// (copy c&3 makes any col 8B-aligned -> 2x ds_read_b64); Xi staging
// deleted; 3 chunks (8 pre-pool rows, 4 tiles/wave); C7 halved (real oc
// only, stride 12); barriers 22->15; LDS 29.2->22.9KB -> 7 blocks/CU.
__global__ __launch_bounds__(TPB) void fused_forward(
    const float* __restrict__ x,
    const float* __restrict__ kf_w1, const float* __restrict__ kf_b1,
    const float* __restrict__ kf_w2, const float* __restrict__ kf_b2,
    const float* __restrict__ kf_fc1_w, const float* __restrict__ kf_fc1_b,
    const float* __restrict__ kf_fc2_w, const float* __restrict__ kf_fc2_b,
    const float* __restrict__ conv2_w, const float* __restrict__ conv2_b,
    const float* __restrict__ fc1_w, const float* __restrict__ fc1_b,
    const float* __restrict__ fc2_w, const float* __restrict__ fc2_b,
    const unsigned short* __restrict__ wsu,
    float* __restrict__ out)
{
    __shared__ __align__(16) float sm[SM_TOT];
    const int tid = threadIdx.x;
    const int n = blockIdx.x;

    const float bias1 = kf_b1[tid & 7];   // hoisted for conv7 pool
    const int l  = tid & 63, wv = tid >> 6;
    const int lm = l & 15, lk = l >> 4;

    // hoist conv7 A-frags: 2 global 16B loads cover ALL of conv7
    bf16x8 A7_0, A7_1;
    {
        const unsigned short* W7 = wsu + W7U;
        A7_0 = *(const bf16x8*)(W7 + lm * 32 + lk * 8);
        A7_1 = *(const bf16x8*)(W7 + 512 + lm * 32 + lk * 8);
    }

    // ---- stage 0: x f32 (float4) ----
    {
        const float4* xg = (const float4*)(x + (long long)n * 784);
        float4* d = (float4*)&sm[OX];
        for (int i = tid; i < 196; i += TPB) d[i] = xg[i];
    }
    __syncthreads();

    // ---- build xbf4: copy s entry (r,m) = x[r][m+s], pads 0 ----
    {
        unsigned short* xb = (unsigned short*)&sm[OXB];
        #pragma unroll
        for (int i = 0; i < 20; ++i) {
            int e = i * 192 + tid;              // 0..3839
            int s = e / 960, rem = e - s * 960;
            int r = rem >> 5, m = rem & 31;
            int c = m + s;
            float v = (r < 28 && c < 28) ? sm[OX + r * 28 + c] : 0.f;
            xb[s * 968 + rem] = f2bf(v);
        }
    }
    __syncthreads();

    // ---- conv7 via MFMA: 3 chunks x {MFMA 4 tiles/wave | bar | pool | bar}
    // chunk g covers pre-pool rows 8g..8g+7 (n = lr*24 + col, col 0..21 real).
    for (int g = 0; g < 3; ++g) {
        {
            const unsigned short* xb = (const unsigned short*)&sm[OXB];
            float* C7 = &sm[OC7];
            #pragma unroll
            for (int j = 0; j < 4; ++j) {
                int nn = (wv * 4 + j) * 16 + lm;
                int lr = nn / 24, c = nn - lr * 24;
                int s = c & 3, q = c - s;
                f32x4 acc = {0.f, 0.f, 0.f, 0.f};
                #pragma unroll
                for (int s4 = 0; s4 < 2; ++s4) {
                    int rb = 8 * g + lr + s4 * 4 + lk;   // ky = s4*4+lk
                    rb = rb > 29 ? 29 : rb;              // pad rows (zeros)
                    const unsigned short* p = xb + s * 968 + rb * 32 + q;
                    short4 lo = *(const short4*)p;       // 8B-aligned
                    short4 hi = *(const short4*)(p + 4);
                    bf16x8 B;
                    B[0] = lo.x; B[1] = lo.y; B[2] = lo.z; B[3] = lo.w;
                    B[4] = hi.x; B[5] = hi.y; B[6] = hi.z; B[7] = hi.w;
                    acc = __builtin_amdgcn_mfma_f32_16x16x32_bf16(
                        s4 ? A7_1 : A7_0, B, acc, 0, 0, 0);
                }
                if (lk < 2)                              // real oc 0..7 only
                    *(f32x4*)(C7 + nn * 12 + lk * 4) = acc;
            }
        }
        __syncthreads();

        // pool: pooled rows p = 4g+plr (plr 0..3); 176 thr x 2 outputs
        if (tid < 176) {
            int oc = tid & 7, qq = tid >> 3;      // qq 0..21
            int c = qq % 11, plr2 = qq / 11;      // 0,1
            const float* C7 = &sm[OC7];
            unsigned short* c1b = (unsigned short*)&sm[OC1B];
            #pragma unroll
            for (int hh = 0; hh < 2; ++hh) {
                int plr = plr2 + 2 * hh;
                int p = 4 * g + plr;
                if (p < 11) {
                    int nb = (2 * plr) * 24 + 2 * c;
                    float v00 = C7[nb * 12 + oc];
                    float v01 = C7[(nb + 1) * 12 + oc];
                    float v10 = C7[(nb + 24) * 12 + oc];
                    float v11 = C7[(nb + 25) * 12 + oc];
                    float m = fmaxf(fmaxf(v00, v01), fmaxf(v10, v11)) + bias1;
                    c1b[p * 96 + c * 8 + oc] = f2bf(fmaxf(m, 0.f));
                }
            }
        }
        __syncthreads();
    }

    // ---- conv5 via MFMA: 3 waves x 1 N-tile x 7 k-steps -> C5[48][20] ----
    {
        int nn = wv * 16 + lm;
        int nc = nn > 35 ? 35 : nn;            // clamp pad lanes (garbage ok)
        const int rr = nc / 6, cc = nc - rr * 6;
        const unsigned short* c1b = (const unsigned short*)&sm[OC1B];
        const char* W5 = (const char*)(wsu + W5U);
        f32x4 acc = {0.f, 0.f, 0.f, 0.f};
        #pragma unroll
        for (int s = 0; s < 7; ++s) {
            int tap = 4 * s + lk;
            int ky = (tap * 13) >> 6;          // tap/5 for tap<=27
            int kx = tap - ky * 5;
            bf16x8 A = *(const bf16x8*)(W5 + s * 1024 + lm * 64 + lk * 16);
            bf16x8 B = *(const bf16x8*)(c1b + (rr + ky) * 96 + (cc + kx) * 8);
            acc = __builtin_amdgcn_mfma_f32_16x16x32_bf16(A, B, acc, 0, 0, 0);
        }
        *(f32x4*)(&sm[OC5] + nn * 20 + lk * 4) = acc;
    }
    __syncthreads();

    // ---- conv5 pool: C5 pre-pool 6x6 -> f[10][9] + bias + relu ----
    if (tid < 90) {
        int oc = tid % 10, rr = tid / 10;      // rr = py*3+px
        int py = rr / 3, px = rr % 3;
        const float* C5 = &sm[OC5];
        int nb = (2 * py) * 6 + 2 * px;
        float v = fmaxf(fmaxf(C5[nb * 20 + oc], C5[(nb + 1) * 20 + oc]),
                        fmaxf(C5[(nb + 6) * 20 + oc], C5[(nb + 7) * 20 + oc]));
        sm[OF + oc * 9 + rr] = fmaxf(v + kf_b2[oc], 0.f);
    }
    __syncthreads();

    // ---- wave 0: fc 90->32 + relu, fc 32->40 (no barrier between);
    //      waves 1-2: zero y2 [784,2656) (f/h at 5552+ untouched) ----
    if (tid < 32) {
        float acc = kf_fc1_b[tid];
        const float2* wr = (const float2*)&kf_fc1_w[tid * 90];
        const float2* ff = (const float2*)&sm[OF];
        for (int i = 0; i < 45; ++i) {
            float2 wv2 = wr[i], fv = ff[i];
            acc = fmaf(wv2.x, fv.x, acc);
            acc = fmaf(wv2.y, fv.y, acc);
        }
        sm[OH + tid] = fmaxf(acc, 0.f);
    }
    if (tid < 40) {
        float acc = kf_fc2_b[tid];
        const float4* wr = (const float4*)&kf_fc2_w[tid * 32];
        const float4* hh = (const float4*)&sm[OH];
        #pragma unroll
        for (int i = 0; i < 8; ++i) {
            float4 wv2 = wr[i], hv = hh[i];
            acc = fmaf(wv2.x, hv.x, acc);
            acc = fmaf(wv2.y, hv.y, acc);
            acc = fmaf(wv2.z, hv.z, acc);
            acc = fmaf(wv2.w, hv.w, acc);
        }
        sm[OK2 + tid] = acc;
    }
    if (tid >= 64) {
        float4* z4 = (float4*)&sm[OY2];          // 1872 f = 468 float4
        for (int i = tid - 64; i < 468; i += 128) z4[i] = float4{0.f, 0.f, 0.f, 0.f};
    }
    __syncthreads();

    // ---- dynamic 2x2 conv + pool + relu -> y2 bf16 [row][col][ic] ----
    if (tid < 120) {
        int oc = tid % 10, py = tid / 10;      // py 0..11
        float4 kv = *(const float4*)&sm[OK2 + oc * 4];
        float k0 = kv.x, k1 = kv.y, k2 = kv.z, k3 = kv.w;
        const float* x0 = &sm[OX + 2 * py * 28];
        const float* x1 = x0 + 28;
        const float* x2 = x0 + 56;
        float2 q0 = *(const float2*)&x0[0];
        float2 q1 = *(const float2*)&x1[0];
        float2 q2 = *(const float2*)&x2[0];
        float A0 = q0.x, B0 = q0.y;
        float A1 = q1.x, B1 = q1.y;
        float A2 = q2.x, B2 = q2.y;
        unsigned short* y2 = (unsigned short*)&sm[OY2];
        #pragma unroll
        for (int j = 0; j < 12; ++j) {
            float2 r0 = *(const float2*)&x0[2 * j + 2];
            float2 r1 = *(const float2*)&x1[2 * j + 2];
            float2 r2v = *(const float2*)&x2[2 * j + 2];
            float C0 = r0.x, C1 = r1.x, C2 = r2v.x;
            float c00 = A0 * k0 + B0 * k1 + A1 * k2 + B1 * k3;
            float c01 = B0 * k0 + C0 * k1 + B1 * k2 + C1 * k3;
            float c10 = A1 * k0 + B1 * k1 + A2 * k2 + B2 * k3;
            float c11 = B1 * k0 + C1 * k1 + B2 * k2 + C2 * k3;
            float m = fmaxf(fmaxf(c00, c01), fmaxf(c10, c11));
            y2[py * 288 + j * 24 + oc] = f2bf(fmaxf(m, 0.f));
            A0 = C0; A1 = C1; A2 = C2;
            B0 = r0.y; B1 = r1.y; B2 = r2v.y;
        }
    }
    __syncthreads();

    // ---- conv2 via MFMA: 2 waves x {2 M x 2 N tiles}; 15 k-steps ----
    if (wv < 2) {
        f32x4 a00 = {0.f, 0.f, 0.f, 0.f};
        f32x4 a01 = a00, a10 = a00, a11 = a00;
        const char* W3 = (const char*)(wsu + W3U);
        const int aoff0 = lm * 64 + lk * 16;
        const int oc1 = 16 + (lm < 4 ? lm : 3);    // clamp: rows 20+ unused
        const int aoff1 = oc1 * 64 + lk * 16;
        const int n0 = wv * 32 + lm;
        const int n1 = n0 + 16;
        const int kyip = l >> 5, icb = (lk & 1) * 8;
        const unsigned short* Y2 = (const unsigned short*)&sm[OY2];
        const int b0 = ((n0 >> 3) + kyip) * 288 + (n0 & 7) * 24 + icb;
        const int b1 = ((n1 >> 3) + kyip) * 288 + (n1 & 7) * 24 + icb;
        #pragma unroll
        for (int p = 0; p < 3; ++p) {
            #pragma unroll
            for (int kx = 0; kx < 5; ++kx) {
                const char* wa = W3 + (kx * 3 + p) * 1280;
                bf16x8 A0 = *(const bf16x8*)(wa + aoff0);
                bf16x8 A1 = *(const bf16x8*)(wa + aoff1);
                const int bo = p * 576 + kx * 24;      // bf16 units
                bf16x8 B0 = *(const bf16x8*)(Y2 + b0 + bo);
                bf16x8 B1 = *(const bf16x8*)(Y2 + b1 + bo);
                a00 = __builtin_amdgcn_mfma_f32_16x16x32_bf16(A0, B0, a00, 0, 0, 0);
                a01 = __builtin_amdgcn_mfma_f32_16x16x32_bf16(A0, B1, a01, 0, 0, 0);
                a10 = __builtin_amdgcn_mfma_f32_16x16x32_bf16(A1, B0, a10, 0, 0, 0);
                a11 = __builtin_amdgcn_mfma_f32_16x16x32_bf16(A1, B1, a11, 0, 0, 0);
            }
        }
        float* C = &sm[OC2S];
        *(f32x4*)(C + n0 * 36 + lk * 4)      = a00;    // oc 0..15
        *(f32x4*)(C + n1 * 36 + lk * 4)      = a01;
        *(f32x4*)(C + n0 * 36 + 16 + lk * 4) = a10;    // oc 16..19 (+junk)
        *(f32x4*)(C + n1 * 36 + 16 + lk * 4) = a11;
    }
    __syncthreads();

    // ---- pool C[64][36] + bias + relu -> p3[20,4,4] (80 threads) ----
    if (tid < 80) {
        int oc = tid % 20, py = tid / 20;      // py 0..3
        float b = conv2_b[oc];
        const float* C = &sm[OC2S];
        #pragma unroll
        for (int px = 0; px < 4; ++px) {
            int n00 = (2 * py) * 8 + 2 * px;
            float c00 = C[n00 * 36 + oc];
            float c01 = C[(n00 + 1) * 36 + oc];
            float c10 = C[(n00 + 8) * 36 + oc];
            float c11 = C[(n00 + 9) * 36 + oc];
            float m = fmaxf(fmaxf(c00, c01), fmaxf(c10, c11)) + b;
            sm[OP3 + oc * 16 + py * 4 + px] = fmaxf(m, 0.f);
        }
    }
    __syncthreads();

    // ---- fc 320->50, 2-way k-split (100 threads, 40 float4 each) ----
    if (tid < 100) {
        int g = tid / 50, o = tid % 50;
        const float4* wr4 = (const float4*)&fc1_w[o * 320 + g * 160];
        const float4* pp4 = (const float4*)&sm[OP3 + g * 160];
        float acc = 0.f;
        for (int i = 0; i < 40; ++i) {
            float4 wv2 = wr4[i], pv = pp4[i];
            acc = fmaf(wv2.x, pv.x, acc);
            acc = fmaf(wv2.y, pv.y, acc);
            acc = fmaf(wv2.z, pv.z, acc);
            acc = fmaf(wv2.w, pv.w, acc);
        }
        sm[OPF + tid] = acc;
    }
    __syncthreads();

    // ---- tail: wave 0, barrier-free (intra-wave LDS ordering) ----
    if (tid < 50) {
        float acc = fc1_b[tid] + sm[OPF + tid] + sm[OPF + 50 + tid];
        sm[OA1 + tid] = fmaxf(acc, 0.f);
    }
    if (tid < 10) {
        float acc = fc2_b[tid];
        const float2* wr = (const float2*)&fc2_w[tid * 50];
        #pragma unroll
        for (int i = 0; i < 25; ++i) {
            float2 wv2 = wr[i];
            acc = fmaf(wv2.x, sm[OA1 + 2 * i], acc);
            acc = fmaf(wv2.y, sm[OA1 + 2 * i + 1], acc);
        }
        sm[OZ + tid] = acc;
    }
    if (tid < 10) {
        float m = sm[OZ + 0];
        #pragma unroll
        for (int i = 1; i < 10; ++i) m = fmaxf(m, sm[OZ + i]);
        float s = 0.f;
        #pragma unroll
        for (int i = 0; i < 10; ++i) s += expf(sm[OZ + i] - m);
        out[n * 10 + tid] = sm[OZ + tid] - m - logf(s);
    }
}

extern "C" void kernel_launch(void* const* d_in, const int* in_sizes, int n_in,
                              void* d_out, int out_size, void* d_ws, size_t ws_size,
                              hipStream_t stream) {
    const float* x        = (const float*)d_in[0];
    const float* kf_w1    = (const float*)d_in[1];
    const float* kf_b1    = (const float*)d_in[2];
    const float* kf_w2    = (const float*)d_in[3];
    const float* kf_b2    = (const float*)d_in[4];
    const float* kf_fc1_w = (const float*)d_in[5];
    const float* kf_fc1_b = (const float*)d_in[6];
    const float* kf_fc2_w = (const float*)d_in[7];
    const float* kf_fc2_b = (const float*)d_in[8];
    const float* conv2_w  = (const float*)d_in[9];
    const float* conv2_b  = (const float*)d_in[10];
    const float* fc1_w    = (const float*)d_in[11];
    const float* fc1_b    = (const float*)d_in[12];
    const float* fc2_w    = (const float*)d_in[13];
    const float* fc2_b    = (const float*)d_in[14];

    const int N = in_sizes[0] / 784;   // 8192

    unsigned short* wsu = (unsigned short*)d_ws;   // 28416 B <= ws floor
    repack_w<<<(WSU_TOT + 255) / 256, 256, 0, stream>>>(conv2_w, kf_w2, kf_w1, wsu);

    fused_forward<<<N, TPB, 0, stream>>>(
        x, kf_w1, kf_b1, kf_w2, kf_b2, kf_fc1_w, kf_fc1_b, kf_fc2_w, kf_fc2_b,
        conv2_w, conv2_b, fc1_w, fc1_b, fc2_w, fc2_b, wsu, (float*)d_out);
}